// Round 10
// baseline (34092.471 us; speedup 1.0000x reference)
//
#include <hip/hip_runtime.h>
#include <math.h>

#define HDIM 96
#define SDIM 48
#define FDIM 24
#define KA   312      // 2H + 2S + F
#define WATT 192
#define KG   288      // 3H

// ===========================================================================
// Edge MLPs (both directions), fp32. 16 edges/block, 256 threads.
// Writes pe (ws), denom (ws), out_revw (float chunk 2).
// ===========================================================================
__global__ __launch_bounds__(256) void t_edge(
    const float* __restrict__ x, const float* __restrict__ xs,
    const float* __restrict__ ef, const int* __restrict__ ei,
    const float* __restrict__ fW1, const float* __restrict__ fb1,
    const float* __restrict__ fW2, const float* __restrict__ fb2,
    const float* __restrict__ rW1, const float* __restrict__ rb1,
    const float* __restrict__ rW2, const float* __restrict__ rb2,
    float* __restrict__ pe, float* __restrict__ denom,
    float* __restrict__ out_revw, int N, int E)
{
  __shared__ __align__(16) float feat[16][KA];
  __shared__ float score[16];
  const int tid = threadIdx.x;
  const int e0 = blockIdx.x * 16;

  for (int mlp = 0; mlp < 2; ++mlp) {
    {
      const int el = tid >> 4, sub = tid & 15;
      const int e = min(e0 + el, E - 1);
      int a = ei[e], b = ei[(size_t)E + e];        // a=src, b=dest
      a = min(max(a, 0), N - 1); b = min(max(b, 0), N - 1);
      if (mlp) { const int t = a; a = b; b = t; }  // rev: s=dest, d=src
      for (int k = sub; k < KA; k += 16) {
        float v;
        if (k < 96)       v = x[(size_t)a * 96 + k];
        else if (k < 192) v = x[(size_t)b * 96 + (k - 96)];
        else if (k < 240) v = xs[(size_t)a * 48 + (k - 192)];
        else if (k < 288) v = xs[(size_t)b * 48 + (k - 240)];
        else              v = ef[(size_t)e * 24 + (k - 288)];
        feat[el][k] = v;
      }
    }
    if (tid < 16) score[tid] = 0.f;
    __syncthreads();

    const float* W1 = mlp ? rW1 : fW1;
    const float* b1 = mlp ? rb1 : fb1;
    const float* W2 = mlp ? rW2 : fW2;
    for (int i = 0; i < 12; ++i) {
      const int u = i * 256 + tid;                 // 16 edges x 192 units
      const int el = u / 192, n = u - el * 192;
      const float4* fr = (const float4*)feat[el];
      const float4* wr = (const float4*)(W1 + (size_t)n * KA);
      float h = 0.f;
      for (int k4 = 0; k4 < KA / 4; ++k4) {
        const float4 f4 = fr[k4], w4 = wr[k4];
        h += f4.x * w4.x + f4.y * w4.y + f4.z * w4.z + f4.w * w4.w;
      }
      h += b1[n];
      if (h > 0.f) atomicAdd(&score[el], h * W2[n]);
    }
    __syncthreads();

    if (tid < 16 && e0 + tid < E) {
      const int e = e0 + tid;
      const float raw = score[tid] + (mlp ? rb2[0] : fb2[0]);
      if (mlp == 0) {
        const float lr = raw > 0.f ? raw : 0.01f * raw;     // leaky_relu
        const float p = __expf(lr * 0.10206207261596575f);  // /sqrt(96)
        pe[e] = p;
        const int d = min(max(ei[(size_t)E + e], 0), N - 1);
        unsafeAtomicAdd(&denom[d], p);
      } else {
        out_revw[e] = 1.f / (1.f + __expf(-raw));
      }
    }
    __syncthreads();
  }
}

// ===========================================================================
// Normalize + scatter-aggregate. One thread per (edge, channel-pair).
// Writes out_fwdw (float chunk 1) and fwdm/revm (ws).
// ===========================================================================
__global__ __launch_bounds__(256) void t_agg(
    const float* __restrict__ x, const int* __restrict__ ei,
    const float* __restrict__ pe, const float* __restrict__ out_revw,
    const float* __restrict__ denom,
    float* __restrict__ fwdm, float* __restrict__ revm,
    float* __restrict__ out_fwdw, int N, int E)
{
  const long long g = (long long)blockIdx.x * 256 + threadIdx.x;
  const int e = (int)(g / 48);
  if (e >= E) return;
  const int c2 = (int)(g - (long long)e * 48);
  const int s = min(max(ei[e], 0), N - 1);
  const int d = min(max(ei[(size_t)E + e], 0), N - 1);
  const float w = pe[e] / (denom[d] + 1e-9f);
  if (c2 == 0) out_fwdw[e] = w;
  const float rw = out_revw[e];
  const float2 xs2 = *(const float2*)(x + (size_t)s * 96 + 2 * c2);
  const float2 xd2 = *(const float2*)(x + (size_t)d * 96 + 2 * c2);
  unsafeAtomicAdd(&fwdm[(size_t)d * 96 + 2 * c2],     xs2.x * w);
  unsafeAtomicAdd(&fwdm[(size_t)d * 96 + 2 * c2 + 1], xs2.y * w);
  unsafeAtomicAdd(&revm[(size_t)s * 96 + 2 * c2],     xd2.x * rw);
  unsafeAtomicAdd(&revm[(size_t)s * 96 + 2 * c2 + 1], xd2.y * rw);
}

// ===========================================================================
// Node MLPs: r, z, cand + GRU. 16 nodes/block.
// Writes update (chunk 0), z (chunk 3), r (chunk 4) — all float32.
// ===========================================================================
__global__ __launch_bounds__(256) void t_node(
    const float* __restrict__ x,
    const float* __restrict__ fwdm, const float* __restrict__ revm,
    const float* __restrict__ gW1, const float* __restrict__ gb1,
    const float* __restrict__ gW2, const float* __restrict__ gb2,
    const float* __restrict__ uW1, const float* __restrict__ ub1,
    const float* __restrict__ uW2, const float* __restrict__ ub2,
    const float* __restrict__ cW1, const float* __restrict__ cb1,
    const float* __restrict__ cW2, const float* __restrict__ cb2,
    float* __restrict__ out_update, float* __restrict__ out_z,
    float* __restrict__ out_r, int N)
{
  __shared__ __align__(16) float g[16][KG];
  __shared__ __align__(16) float H[16][KG];
  __shared__ float rg[16][96], zg[16][96];
  const int tid = threadIdx.x;
  const int n0 = blockIdx.x * 16;

  {
    const int nl = tid >> 4, sub = tid & 15;
    const int node = min(n0 + nl, N - 1);
    for (int k = sub; k < KG; k += 16) {
      float v;
      if (k < 96)       v = x[(size_t)node * 96 + k];
      else if (k < 192) v = fwdm[(size_t)node * 96 + (k - 96)];
      else              v = revm[(size_t)node * 96 + (k - 192)];
      g[nl][k] = v;
    }
  }
  __syncthreads();

  for (int mlp = 0; mlp < 3; ++mlp) {
    const float* W1 = mlp == 0 ? gW1 : mlp == 1 ? uW1 : cW1;
    const float* b1 = mlp == 0 ? gb1 : mlp == 1 ? ub1 : cb1;
    const float* W2 = mlp == 0 ? gW2 : mlp == 1 ? uW2 : cW2;
    const float* b2 = mlp == 0 ? gb2 : mlp == 1 ? ub2 : cb2;
    if (mlp == 2) {
      for (int u = tid; u < 16 * 96; u += 256) {
        const int el = u / 96, m = u - el * 96;
        g[el][m] *= rg[el][m];                  // cand input: r * x
      }
      __syncthreads();
    }
    // layer1: 288 -> 288, relu
    for (int i = 0; i < 18; ++i) {
      const int u = i * 256 + tid;
      const int el = u / KG, n = u - el * KG;
      const float4* gr = (const float4*)g[el];
      const float4* wr = (const float4*)(W1 + (size_t)n * KG);
      float h = 0.f;
      for (int k4 = 0; k4 < KG / 4; ++k4) {
        const float4 a4 = gr[k4], w4 = wr[k4];
        h += a4.x * w4.x + a4.y * w4.y + a4.z * w4.z + a4.w * w4.w;
      }
      h += b1[n];
      H[el][n] = h > 0.f ? h : 0.f;
    }
    __syncthreads();
    // layer2: 288 -> 96
    for (int i = 0; i < 6; ++i) {
      const int u = i * 256 + tid;
      const int el = u / 96, m = u - el * 96;
      const float4* hr = (const float4*)H[el];
      const float4* wr = (const float4*)(W2 + (size_t)m * KG);
      float v = 0.f;
      for (int k4 = 0; k4 < KG / 4; ++k4) {
        const float4 a4 = hr[k4], w4 = wr[k4];
        v += a4.x * w4.x + a4.y * w4.y + a4.z * w4.z + a4.w * w4.w;
      }
      v += b2[m];
      const int node = n0 + el;
      if (mlp == 0) {
        const float sg = 1.f / (1.f + __expf(-v));
        rg[el][m] = sg;
        if (node < N) out_r[(size_t)node * 96 + m] = sg;
      } else if (mlp == 1) {
        const float sg = 1.f / (1.f + __expf(-v));
        zg[el][m] = sg;
        if (node < N) out_z[(size_t)node * 96 + m] = sg;
      } else if (node < N) {
        const float z  = zg[el][m];
        const float ct = tanhf(v);
        const float xv = x[(size_t)node * 96 + m];
        out_update[(size_t)node * 96 + m] = (1.f - z) * xv + z * ct;
      }
    }
    __syncthreads();
  }
}

__global__ void sentinel_kernel(float* out, int n, float val) {
  const int i = blockIdx.x * 256 + threadIdx.x;
  if (i < n) out[i] = val;
}

// ---------------------------------------------------------------------------
extern "C" void kernel_launch(void* const* d_in, const int* in_sizes, int n_in,
                              void* d_out, int out_size, void* d_ws, size_t ws_size,
                              hipStream_t stream) {
  const float* x  = (const float*)d_in[0];
  const float* xs = (const float*)d_in[1];
  const float* ef = (const float*)d_in[2];
  const int*   ei = (const int*)d_in[3];

  const int N = in_sizes[0] / HDIM;
  const int E = in_sizes[3] / 2;

  float* out = (float*)d_out;          // OUTPUT IS FLOAT32 (R9 finding)

  const bool sizes_ok =
      n_in == 24 &&
      in_sizes[0] == N * HDIM && in_sizes[1] == N * SDIM &&
      in_sizes[2] == E * FDIM && in_sizes[3] == 2 * E &&
      in_sizes[4] == WATT * KA && in_sizes[5] == WATT &&
      in_sizes[6] == WATT && in_sizes[7] == 1 &&
      in_sizes[12] == KG * KG && in_sizes[13] == KG &&
      in_sizes[14] == HDIM * KG && in_sizes[15] == HDIM &&
      out_size == 3 * N * HDIM + 2 * E;
  if (!sizes_ok) {
    sentinel_kernel<<<(out_size + 255) / 256, 256, 0, stream>>>(out, out_size, 777.0f);
    return;
  }

  // ws: pe[E] | denom[N] | fwdm[N*96] | revm[N*96]
  const size_t needed = ((size_t)E + N + 2 * (size_t)N * HDIM) * sizeof(float);
  if (ws_size < needed) {
    sentinel_kernel<<<(out_size + 255) / 256, 256, 0, stream>>>(out, out_size, 12345.0f);
    return;
  }
  float* pe    = (float*)d_ws;
  float* denom = pe + E;
  float* fwdm  = denom + N;
  float* revm  = fwdm + (size_t)N * HDIM;

  float* out_update = out;                         // [N,96]
  float* out_fwdw   = out + (size_t)N * HDIM;      // [E]
  float* out_revw   = out_fwdw + E;                // [E]
  float* out_z      = out_revw + E;                // [N,96]
  float* out_r      = out_z + (size_t)N * HDIM;    // [N,96]

  // zero denom + fwdm + revm (contiguous)
  (void)hipMemsetAsync(denom, 0,
      ((size_t)N + 2 * (size_t)N * HDIM) * sizeof(float), stream);

  t_edge<<<(E + 15) / 16, 256, 0, stream>>>(
      x, xs, ef, ei,
      (const float*)d_in[4], (const float*)d_in[5],
      (const float*)d_in[6], (const float*)d_in[7],
      (const float*)d_in[8], (const float*)d_in[9],
      (const float*)d_in[10], (const float*)d_in[11],
      pe, denom, out_revw, N, E);

  const long long agg_threads = (long long)E * 48;
  t_agg<<<(int)((agg_threads + 255) / 256), 256, 0, stream>>>(
      x, ei, pe, out_revw, denom, fwdm, revm, out_fwdw, N, E);

  t_node<<<(N + 15) / 16, 256, 0, stream>>>(
      x, fwdm, revm,
      (const float*)d_in[12], (const float*)d_in[13],
      (const float*)d_in[14], (const float*)d_in[15],
      (const float*)d_in[16], (const float*)d_in[17],
      (const float*)d_in[18], (const float*)d_in[19],
      (const float*)d_in[20], (const float*)d_in[21],
      (const float*)d_in[22], (const float*)d_in[23],
      out_update, out_z, out_r, N);
}

// Round 11
// 4243.222 us; speedup vs baseline: 8.0346x; 8.0346x over previous
//
#include <hip/hip_runtime.h>
#include <math.h>

typedef unsigned short u16;
typedef unsigned int   u32;

#define HDIM 96
#define SDIM 48
#define FDIM 24
#define KA   312      // 2H + 2S + F
#define WATT 192
#define KG   288      // 3H

// edge MFMA tiling
#define AS_E  328     // edge A LDS row stride in u16 (656 B, 16B-aligned)
#define KT_A  10      // K-steps of 32 (K padded 312 -> 320)
#define KT_G  9       // node K-steps (288)

typedef __attribute__((ext_vector_type(8))) __bf16 bf16x8;
typedef __attribute__((ext_vector_type(4))) float  f32x4;

__device__ __forceinline__ u16 f2bf(float f) {
  u32 u = __float_as_uint(f);
  u = (u + 0x7FFFu + ((u >> 16) & 1u)) >> 16;   // RNE
  return (u16)u;
}
__device__ __forceinline__ u32 pack2(float a, float b) {
  return (u32)f2bf(a) | ((u32)f2bf(b) << 16);
}
__device__ __forceinline__ f32x4 mfma_bf16(bf16x8 a, bf16x8 b, f32x4 c) {
  return __builtin_amdgcn_mfma_f32_16x16x32_bf16(a, b, c, 0, 0, 0);
}

// ===========================================================================
// Edge kernel (MFMA): 64 edges/block, 256 threads (4 waves).
// A = feat [64 x 320] bf16 in LDS (fp32 inputs converted). For mlp in
// {fwd, rev}: GEMM vs W1 [320 x 192] via 16x16x32 MFMA; wave w owns N-tiles
// {3w..3w+2}, all 4 M-tiles. rev reuses the SAME A-tile: rev_W1's input dim
// is permuted during staging (sigma on fp32-pairs: [0,48)<->[48,96),
// [96,120)<->[120,144)). Epilogue fuses bias+relu+dot(W2)+b2 ->
// softmax-exp (fwd: pe + denom atomic) / sigmoid (rev: fp32 out chunk 2).
// ===========================================================================
__global__ __launch_bounds__(256) void edge_kernel(
    const float* __restrict__ x, const float* __restrict__ xs,
    const float* __restrict__ ef, const int* __restrict__ ei,
    const float* __restrict__ fW1, const float* __restrict__ fb1,
    const float* __restrict__ fW2, const float* __restrict__ fb2,
    const float* __restrict__ rW1, const float* __restrict__ rb1,
    const float* __restrict__ rW2, const float* __restrict__ rb2,
    float* __restrict__ pe, float* __restrict__ denom,
    float* __restrict__ out_revw, int N, int E)
{
  __shared__ __align__(16) u16 Alds[64 * AS_E];   // 41,984 B
  __shared__ __align__(16) u16 Blds[WATT * 32];   // 12,288 B
  __shared__ float red[4][64];                    //  1,024 B

  const int tid  = threadIdx.x;
  const int wave = tid >> 6, lane = tid & 63;
  const int q = lane >> 4, c = lane & 15;
  const int e0 = blockIdx.x * 64;

  // ---- gather A as bf16 pairs (pair index p in [0,160), pad >=156 zero) ---
  {
    u32* Aw = (u32*)Alds;
    const int el = tid >> 2, sub = tid & 3;
    const int e = min(e0 + el, E - 1);
    int s = ei[e], d = ei[(size_t)E + e];
    s = min(max(s, 0), N - 1); d = min(max(d, 0), N - 1);
    for (int p = sub; p < 160; p += 4) {
      const int j = 2 * p;                        // fp32 element index
      float2 v = make_float2(0.f, 0.f);
      if (j < 96)       v = *(const float2*)(x  + (size_t)s * 96 + j);
      else if (j < 192) v = *(const float2*)(x  + (size_t)d * 96 + (j - 96));
      else if (j < 240) v = *(const float2*)(xs + (size_t)s * 48 + (j - 192));
      else if (j < 288) v = *(const float2*)(xs + (size_t)d * 48 + (j - 240));
      else if (j < 312) v = *(const float2*)(ef + (size_t)e * 24 + (j - 288));
      Aw[el * (AS_E / 2) + p] = pack2(v.x, v.y);
    }
  }

  for (int mlp = 0; mlp < 2; ++mlp) {
    const float* W1f = mlp ? rW1 : fW1;
    f32x4 acc[4][3];
    for (int m = 0; m < 4; ++m)
      for (int t = 0; t < 3; ++t)
        acc[m][t] = (f32x4){0.f, 0.f, 0.f, 0.f};

    for (int kt = 0; kt < KT_A; ++kt) {
      __syncthreads();                  // prev compute / gather done
      u32* Bw = (u32*)Blds;
      for (int j = tid; j < WATT * 16; j += 256) {
        const int n = j >> 4, kk = j & 15;
        const int pd = kt * 16 + kk;    // feat-space pair index
        u32 v = 0u;
        if (pd < 156) {
          int src = pd;
          if (mlp) {                    // sigma (pair units)
            if (src < 48)       src += 48;
            else if (src < 96)  src -= 48;
            else if (src < 120) src += 24;
            else if (src < 144) src -= 24;
          }
          const float2 w = *(const float2*)(W1f + (size_t)n * KA + 2 * src);
          v = pack2(w.x, w.y);
        }
        Bw[j] = v;
      }
      __syncthreads();

      bf16x8 a[4];
      for (int m = 0; m < 4; ++m)
        a[m] = *(const bf16x8*)&Alds[(m * 16 + c) * AS_E + kt * 32 + q * 8];
      for (int t = 0; t < 3; ++t) {
        const int nt = wave * 3 + t;
        const bf16x8 b = *(const bf16x8*)&Blds[(nt * 16 + c) * 32 + q * 8];
        for (int m = 0; m < 4; ++m)
          acc[m][t] = mfma_bf16(a[m], b, acc[m][t]);
      }
    }

    // ---- epilogue: bias + relu + dot(W2), reduce across 16 col-lanes ----
    const float* b1p = mlp ? rb1 : fb1;
    const float* W2p = mlp ? rW2 : fW2;
    float p[4][4];
    for (int m = 0; m < 4; ++m)
      for (int r = 0; r < 4; ++r) p[m][r] = 0.f;
    for (int t = 0; t < 3; ++t) {
      const int n = (wave * 3 + t) * 16 + c;
      const float b1f = b1p[n];
      const float w2f = W2p[n];
      for (int m = 0; m < 4; ++m)
        for (int r = 0; r < 4; ++r) {
          float h = acc[m][t][r] + b1f;
          h = h > 0.f ? h : 0.f;
          p[m][r] += h * w2f;
        }
    }
    for (int off = 1; off <= 8; off <<= 1)
      for (int m = 0; m < 4; ++m)
        for (int r = 0; r < 4; ++r)
          p[m][r] += __shfl_xor(p[m][r], off, 64);

    __syncthreads();                    // red safe to overwrite
    if (c == 0) {
      for (int m = 0; m < 4; ++m)
        for (int r = 0; r < 4; ++r)
          red[wave][m * 16 + q * 4 + r] = p[m][r];
    }
    __syncthreads();

    if (tid < 64 && e0 + tid < E) {
      float raw = red[0][tid] + red[1][tid] + red[2][tid] + red[3][tid];
      const int e = e0 + tid;
      if (mlp == 0) {
        raw += fb2[0];
        const float lr = raw > 0.f ? raw : 0.01f * raw;      // leaky_relu
        const float pv = __expf(lr * 0.10206207261596575f);  // /sqrt(96)
        pe[e] = pv;
        const int d = min(max(ei[(size_t)E + e], 0), N - 1);
        unsafeAtomicAdd(&denom[d], pv);
      } else {
        raw += rb2[0];
        out_revw[e] = 1.f / (1.f + __expf(-raw));
      }
    }
  }
}

// ===========================================================================
// Normalize + scatter-aggregate (unchanged from R10).
// ===========================================================================
__global__ __launch_bounds__(256) void t_agg(
    const float* __restrict__ x, const int* __restrict__ ei,
    const float* __restrict__ pe, const float* __restrict__ out_revw,
    const float* __restrict__ denom,
    float* __restrict__ fwdm, float* __restrict__ revm,
    float* __restrict__ out_fwdw, int N, int E)
{
  const long long g = (long long)blockIdx.x * 256 + threadIdx.x;
  const int e = (int)(g / 48);
  if (e >= E) return;
  const int c2 = (int)(g - (long long)e * 48);
  const int s = min(max(ei[e], 0), N - 1);
  const int d = min(max(ei[(size_t)E + e], 0), N - 1);
  const float w = pe[e] / (denom[d] + 1e-9f);
  if (c2 == 0) out_fwdw[e] = w;
  const float rw = out_revw[e];
  const float2 xs2 = *(const float2*)(x + (size_t)s * 96 + 2 * c2);
  const float2 xd2 = *(const float2*)(x + (size_t)d * 96 + 2 * c2);
  unsafeAtomicAdd(&fwdm[(size_t)d * 96 + 2 * c2],     xs2.x * w);
  unsafeAtomicAdd(&fwdm[(size_t)d * 96 + 2 * c2 + 1], xs2.y * w);
  unsafeAtomicAdd(&revm[(size_t)s * 96 + 2 * c2],     xd2.x * rw);
  unsafeAtomicAdd(&revm[(size_t)s * 96 + 2 * c2 + 1], xd2.y * rw);
}

// ===========================================================================
// Node MLP (MFMA): 32 nodes/block, 256 threads. A = [x | fwdm | revm] bf16
// (MODE 2: first 96 cols are r*x, r read fp32 from out_r).
// layer1 288->288 -> relu -> Hlds (bf16), layer2 288->96.
// Epilogue: MODE 0 -> sigmoid -> out_r; MODE 1 -> sigmoid -> out_z;
// MODE 2 -> tanh + GRU gate (z from out_z fp32) -> out_update.
// ===========================================================================
template <int MODE>
__global__ __launch_bounds__(256) void node_kernel(
    const float* __restrict__ x,
    const float* __restrict__ fwdm, const float* __restrict__ revm,
    const float* __restrict__ W1, const float* __restrict__ b1,
    const float* __restrict__ W2, const float* __restrict__ b2,
    const float* __restrict__ rin, const float* __restrict__ zin,
    float* __restrict__ fout, int N)
{
  __shared__ __align__(16) u16 Alds[32 * KG];   // 18,432 B
  __shared__ __align__(16) u16 Hlds[32 * KG];   // 18,432 B
  __shared__ __align__(16) u16 Blds[KG * 32];   // 18,432 B (reused for W2)

  const int tid = threadIdx.x;
  const int wave = tid >> 6, lane = tid & 63;
  const int q = lane >> 4, c = lane & 15;
  const int n0 = blockIdx.x * 32;

  // ---- gather A (144 fp32-pairs per node row) ----
  {
    u32* Aw = (u32*)Alds;
    const int nl = tid >> 3, sub = tid & 7;
    const int node = min(n0 + nl, N - 1);
    for (int p = sub; p < 144; p += 8) {
      const int j = 2 * p;
      float2 v;
      if (j < 96) {
        v = *(const float2*)(x + (size_t)node * 96 + j);
        if (MODE == 2) {
          const float2 r2 = *(const float2*)(rin + (size_t)node * 96 + j);
          v.x *= r2.x; v.y *= r2.y;
        }
      } else if (j < 192) {
        v = *(const float2*)(fwdm + (size_t)node * 96 + (j - 96));
      } else {
        v = *(const float2*)(revm + (size_t)node * 96 + (j - 192));
      }
      Aw[nl * (KG / 2) + p] = pack2(v.x, v.y);
    }
  }

  // ---- layer 1: 288 -> 288 ----
  const int ntc = (wave < 2) ? 5 : 4;           // 18 N-tiles over 4 waves
  f32x4 acc[2][5];
  for (int m = 0; m < 2; ++m)
    for (int t = 0; t < 5; ++t) acc[m][t] = (f32x4){0.f, 0.f, 0.f, 0.f};
  for (int kt = 0; kt < KT_G; ++kt) {
    __syncthreads();
    u32* Bw = (u32*)Blds;
    for (int j = tid; j < KG * 16; j += 256) {
      const int n = j >> 4, kk = j & 15;
      const float2 w = *(const float2*)(W1 + (size_t)n * KG + kt * 32 + kk * 2);
      Bw[j] = pack2(w.x, w.y);
    }
    __syncthreads();
    const bf16x8 a0 = *(const bf16x8*)&Alds[c * KG + kt * 32 + q * 8];
    const bf16x8 a1 = *(const bf16x8*)&Alds[(16 + c) * KG + kt * 32 + q * 8];
    for (int t = 0; t < ntc; ++t) {
      const int nt = wave + 4 * t;
      const bf16x8 b = *(const bf16x8*)&Blds[(nt * 16 + c) * 32 + q * 8];
      acc[0][t] = mfma_bf16(a0, b, acc[0][t]);
      acc[1][t] = mfma_bf16(a1, b, acc[1][t]);
    }
  }
  // bias + relu -> Hlds (bf16)
  for (int t = 0; t < ntc; ++t) {
    const int n = (wave + 4 * t) * 16 + c;
    const float b1f = b1[n];
    for (int m = 0; m < 2; ++m)
      for (int r = 0; r < 4; ++r) {
        float h = acc[m][t][r] + b1f;
        h = h > 0.f ? h : 0.f;
        Hlds[(m * 16 + q * 4 + r) * KG + n] = f2bf(h);
      }
  }

  // ---- layer 2: 288 -> 96 ----
  const int ntc2 = (wave < 2) ? 2 : 1;          // 6 N-tiles over 4 waves
  f32x4 acc2[2][2];
  for (int m = 0; m < 2; ++m)
    for (int t = 0; t < 2; ++t) acc2[m][t] = (f32x4){0.f, 0.f, 0.f, 0.f};
  for (int kt = 0; kt < KT_G; ++kt) {
    __syncthreads();                            // guards Hlds completion (kt==0)
    u32* Bw = (u32*)Blds;
    for (int j = tid; j < HDIM * 16; j += 256) {
      const int n = j >> 4, kk = j & 15;
      const float2 w = *(const float2*)(W2 + (size_t)n * KG + kt * 32 + kk * 2);
      Bw[j] = pack2(w.x, w.y);
    }
    __syncthreads();
    const bf16x8 a0 = *(const bf16x8*)&Hlds[c * KG + kt * 32 + q * 8];
    const bf16x8 a1 = *(const bf16x8*)&Hlds[(16 + c) * KG + kt * 32 + q * 8];
    for (int t = 0; t < ntc2; ++t) {
      const int nt = wave + 4 * t;
      const bf16x8 b = *(const bf16x8*)&Blds[(nt * 16 + c) * 32 + q * 8];
      acc2[0][t] = mfma_bf16(a0, b, acc2[0][t]);
      acc2[1][t] = mfma_bf16(a1, b, acc2[1][t]);
    }
  }

  // ---- epilogue ----
  for (int t = 0; t < ntc2; ++t) {
    const int n2 = (wave + 4 * t) * 16 + c;
    const float b2f = b2[n2];
    for (int m = 0; m < 2; ++m)
      for (int r = 0; r < 4; ++r) {
        const int row = m * 16 + q * 4 + r;
        const int node = n0 + row;
        if (node < N) {
          const float v = acc2[m][t][r] + b2f;
          if (MODE < 2) {
            fout[(size_t)node * HDIM + n2] = 1.f / (1.f + __expf(-v));
          } else {
            const float ct = tanhf(v);
            const float z = zin[(size_t)node * HDIM + n2];
            const float xv = x[(size_t)node * HDIM + n2];
            fout[(size_t)node * HDIM + n2] = (1.f - z) * xv + z * ct;
          }
        }
      }
  }
}

__global__ void sentinel_kernel(float* out, int n, float val) {
  const int i = blockIdx.x * 256 + threadIdx.x;
  if (i < n) out[i] = val;
}

// ---------------------------------------------------------------------------
extern "C" void kernel_launch(void* const* d_in, const int* in_sizes, int n_in,
                              void* d_out, int out_size, void* d_ws, size_t ws_size,
                              hipStream_t stream) {
  const float* x  = (const float*)d_in[0];
  const float* xs = (const float*)d_in[1];
  const float* ef = (const float*)d_in[2];
  const int*   ei = (const int*)d_in[3];

  const int N = in_sizes[0] / HDIM;
  const int E = in_sizes[3] / 2;

  float* out = (float*)d_out;          // output buffer is float32 (R9 finding)

  const bool sizes_ok =
      n_in == 24 &&
      in_sizes[0] == N * HDIM && in_sizes[1] == N * SDIM &&
      in_sizes[2] == E * FDIM && in_sizes[3] == 2 * E &&
      in_sizes[4] == WATT * KA && in_sizes[5] == WATT &&
      in_sizes[6] == WATT && in_sizes[7] == 1 &&
      in_sizes[12] == KG * KG && in_sizes[13] == KG &&
      in_sizes[14] == HDIM * KG && in_sizes[15] == HDIM &&
      out_size == 3 * N * HDIM + 2 * E;
  if (!sizes_ok) {
    sentinel_kernel<<<(out_size + 255) / 256, 256, 0, stream>>>(out, out_size, 777.0f);
    return;
  }

  // ws: pe[E] | denom[N] | fwdm[N*96] | revm[N*96]
  const size_t needed = ((size_t)E + N + 2 * (size_t)N * HDIM) * sizeof(float);
  if (ws_size < needed) {
    sentinel_kernel<<<(out_size + 255) / 256, 256, 0, stream>>>(out, out_size, 12345.0f);
    return;
  }
  float* pe    = (float*)d_ws;
  float* denom = pe + E;
  float* fwdm  = denom + N;
  float* revm  = fwdm + (size_t)N * HDIM;

  float* out_update = out;                         // [N,96]
  float* out_fwdw   = out + (size_t)N * HDIM;      // [E]
  float* out_revw   = out_fwdw + E;                // [E]
  float* out_z      = out_revw + E;                // [N,96]
  float* out_r      = out_z + (size_t)N * HDIM;    // [N,96]

  // zero denom + fwdm + revm (contiguous)
  (void)hipMemsetAsync(denom, 0,
      ((size_t)N + 2 * (size_t)N * HDIM) * sizeof(float), stream);

  edge_kernel<<<(E + 63) / 64, 256, 0, stream>>>(
      x, xs, ef, ei,
      (const float*)d_in[4], (const float*)d_in[5],
      (const float*)d_in[6], (const float*)d_in[7],
      (const float*)d_in[8], (const float*)d_in[9],
      (const float*)d_in[10], (const float*)d_in[11],
      pe, denom, out_revw, N, E);

  const long long agg_threads = (long long)E * 48;
  t_agg<<<(int)((agg_threads + 255) / 256), 256, 0, stream>>>(
      x, ei, pe, out_revw, denom, fwdm, revm, out_fwdw, N, E);

  const int nblk = (N + 31) / 32;
  node_kernel<0><<<nblk, 256, 0, stream>>>(
      x, fwdm, revm,
      (const float*)d_in[12], (const float*)d_in[13],
      (const float*)d_in[14], (const float*)d_in[15],
      nullptr, nullptr, out_r, N);
  node_kernel<1><<<nblk, 256, 0, stream>>>(
      x, fwdm, revm,
      (const float*)d_in[16], (const float*)d_in[17],
      (const float*)d_in[18], (const float*)d_in[19],
      nullptr, nullptr, out_z, N);
  node_kernel<2><<<nblk, 256, 0, stream>>>(
      x, fwdm, revm,
      (const float*)d_in[20], (const float*)d_in[21],
      (const float*)d_in[22], (const float*)d_in[23],
      out_r, out_z, out_update, N);
}